// Round 12
// baseline (419.778 us; speedup 1.0000x reference)
//
#include <hip/hip_runtime.h>
#include <hip/hip_bf16.h>

// Problem constants (match reference)
#define N_NODES 50000
#define N_EDGES 800000
#define IN_C 256
#define HID_C 128
#define OUT_C 64

#define NB_SCAN ((N_NODES + 255) / 256)   // 196 blocks of 256 nodes
#define N_BINS ((N_NODES + 127) / 128)    // 391 dst-bins of 128 nodes

// Radix binning pass
#define RB_BLOCK 1024
#define RB_EPT 8
#define RB_CHUNK (RB_BLOCK * RB_EPT)      // 8192 edges per block
#define N_TOT (N_EDGES + N_NODES)         // 850000
#define RB_GRID ((N_TOT + RB_CHUNK - 1) / RB_CHUNK)  // 104

typedef __attribute__((ext_vector_type(8))) short bf16x8;
typedef __attribute__((ext_vector_type(4))) float f32x4;
typedef __attribute__((ext_vector_type(2))) _Float16 f16x2;

__device__ __forceinline__ ushort f2bf(float f) {
    uint u = __float_as_uint(f);
    u += 0x7fff + ((u >> 16) & 1);   // round-to-nearest-even
    return (ushort)(u >> 16);
}
__device__ __forceinline__ float bf2f(ushort h) {
    return __uint_as_float(((uint)h) << 16);
}
// Pack one fp32 value into uint: bf16(hi)<<16 | bf16(residual lo)
__device__ __forceinline__ uint packhl(float v) {
    ushort h = f2bf(v);
    ushort l = f2bf(v - bf2f(h));
    return ((uint)h << 16) | (uint)l;
}

// ---------------------------------------------------------------------------
// Graph preprocessing
// ---------------------------------------------------------------------------

__global__ __launch_bounds__(256) void init_deg_kernel(int* __restrict__ degi,
                                                       int* __restrict__ bincur) {
    int i = blockIdx.x * 256 + threadIdx.x;
    if (i < N_NODES) degi[i] = 1;  // self-loop
    if (i < N_BINS) bincur[i] = 0;
}

__global__ __launch_bounds__(256) void count_deg_kernel(const int* __restrict__ dst,
                                                        int* __restrict__ degi) {
    int e = blockIdx.x * 256 + threadIdx.x;
    if (e < N_EDGES) atomicAdd(&degi[dst[e]], 1);
}

__global__ __launch_bounds__(256) void deg_partial_kernel(const int* __restrict__ degi,
                                                          int* __restrict__ partials) {
    __shared__ int s[256];
    int t = threadIdx.x;
    int i = blockIdx.x * 256 + t;
    s[t] = (i < N_NODES) ? degi[i] : 0;
    __syncthreads();
#pragma unroll
    for (int off = 128; off > 0; off >>= 1) {
        if (t < off) s[t] += s[t + off];
        __syncthreads();
    }
    if (t == 0) partials[blockIdx.x] = s[0];
}

__global__ __launch_bounds__(256) void scan_partials_kernel(const int* __restrict__ partials,
                                                            int* __restrict__ partial_off,
                                                            int* __restrict__ row_ptr) {
    __shared__ int s[256];
    int t = threadIdx.x;
    s[t] = (t < NB_SCAN) ? partials[t] : 0;
    __syncthreads();
#pragma unroll
    for (int off = 1; off < 256; off <<= 1) {
        int x = s[t];
        int add = (t >= off) ? s[t - off] : 0;
        __syncthreads();
        s[t] = x + add;
        __syncthreads();
    }
    if (t < NB_SCAN) partial_off[t] = (t == 0) ? 0 : s[t - 1];
    if (t == 255) row_ptr[N_NODES] = s[255];
}

__global__ __launch_bounds__(256) void scan_final_kernel(const int* __restrict__ degi,
                                                         const int* __restrict__ partial_off,
                                                         int* __restrict__ row_ptr,
                                                         int* __restrict__ cursor,
                                                         float* __restrict__ dis) {
    __shared__ int s[256];
    int t = threadIdx.x;
    int i = blockIdx.x * 256 + t;
    int d = (i < N_NODES) ? degi[i] : 0;
    s[t] = d;
    __syncthreads();
#pragma unroll
    for (int off = 1; off < 256; off <<= 1) {
        int x = s[t];
        int add = (t >= off) ? s[t - off] : 0;
        __syncthreads();
        s[t] = x + add;
        __syncthreads();
    }
    if (i < N_NODES) {
        int excl = partial_off[blockIdx.x] + s[t] - d;
        row_ptr[i] = excl;
        cursor[i] = excl;
        dis[i] = rsqrtf((float)d);
    }
}

// ---------------------------------------------------------------------------
// Two-pass binned CSR build, pass 1 = block-local LDS radix scatter.
// ---------------------------------------------------------------------------

__global__ __launch_bounds__(RB_BLOCK) void bin_scatter_kernel(
    const int* __restrict__ src, const int* __restrict__ dst,
    const int* __restrict__ row_ptr, int* __restrict__ bincur,
    uint* __restrict__ binned) {
    __shared__ int hist[N_BINS];
    __shared__ int cur[N_BINS];
    const int t = threadIdx.x;
    for (int b = t; b < N_BINS; b += RB_BLOCK) hist[b] = 0;
    __syncthreads();

    uint pk[RB_EPT];
    int bn[RB_EPT];
    const int base = blockIdx.x * RB_CHUNK;
#pragma unroll
    for (int k = 0; k < RB_EPT; k++) {
        int i = base + k * RB_BLOCK + t;
        bn[k] = -1;
        if (i < N_TOT) {
            int s, d;
            if (i < N_EDGES) {
                s = src[i];
                d = dst[i];
            } else {
                s = d = i - N_EDGES;
            }
            pk[k] = (uint)s | ((uint)d << 16);
            bn[k] = d >> 7;
            atomicAdd(&hist[bn[k]], 1);
        }
    }
    __syncthreads();

    for (int b = t; b < N_BINS; b += RB_BLOCK) {
        int c = hist[b];
        int g0 = (c > 0) ? atomicAdd(&bincur[b], c) : 0;
        cur[b] = row_ptr[b << 7] + g0;
    }
    __syncthreads();

#pragma unroll
    for (int k = 0; k < RB_EPT; k++) {
        if (bn[k] >= 0) {
            int pos = atomicAdd(&cur[bn[k]], 1);
            binned[pos] = pk[k];
        }
    }
}

// Pass 2: stream bins sequentially; csr slot lands in the bin's contiguous
// ~9 KB region (localized writes). csr_src is ushort (src < 65536).
__global__ __launch_bounds__(256) void csr_scatter_kernel(const uint* __restrict__ binned,
                                                          int* __restrict__ cursor,
                                                          ushort* __restrict__ csr_src) {
    int i = blockIdx.x * 256 + threadIdx.x;
    if (i >= N_TOT) return;
    uint e = binned[i];
    int s = (int)(e & 0xFFFFu);
    int d = (int)(e >> 16);
    int slot = atomicAdd(&cursor[d], 1);
    csr_src[slot] = (ushort)s;
}

// ---------------------------------------------------------------------------
// Weight packing: W[K][N] fp32 -> fragment-ordered bf16 hi/lo
// ---------------------------------------------------------------------------

__global__ __launch_bounds__(64) void pack_w_kernel(const float* __restrict__ W,
                                                    ushort* __restrict__ Ph,
                                                    ushort* __restrict__ Pl,
                                                    int K, int N) {
    int lane = threadIdx.x;
    int CT = N / 16;
    int ct = blockIdx.x % CT;
    int kt = blockIdx.x / CT;
    int lr = lane & 15, lg = lane >> 4;
    size_t base = ((size_t)blockIdx.x * 64 + lane) * 8;
#pragma unroll
    for (int j = 0; j < 8; j++) {
        float w = W[(size_t)(kt * 32 + lg * 8 + j) * N + ct * 16 + lr];
        ushort h = f2bf(w);
        ushort lo = f2bf(w - bf2f(h));
        Ph[base + j] = h;
        Pl[base + j] = lo;
    }
}

// ---------------------------------------------------------------------------
// LDS-free MFMA GEMM, 3-term bf16 split, packed activations.
// wave = 16 rows x 64 cols (CT=4, acc=16 VGPR); block = 4 waves.
// OUT_MODE 0: fp32 + bias (row-major)
// OUT_MODE 1: packed uint + bias (row-major)
// OUT_MODE 2: fp16 * dis[row], SLICE-MAJOR interleaved g[4][M][32]:
//             slice s = global_ct>>1, pos = 2*lr + (global_ct&1)
//             -> lane packs f16x2 from its (even,odd) ct pair; 64B-line stores
// ---------------------------------------------------------------------------

template <int K, int N, int OUT_MODE, bool AF32>
__global__ __launch_bounds__(256) void gemm_mfma_kernel(
    const float* __restrict__ Af, const uint* __restrict__ Ax,
    const ushort* __restrict__ Wph, const ushort* __restrict__ Wpl,
    const float* __restrict__ bias, const float* __restrict__ disp,
    float* __restrict__ Cf, uint* __restrict__ Cx, _Float16* __restrict__ Ch,
    int M) {
    constexpr int CT_TOT = N / 16;        // 8 (N=128) or 4 (N=64)
    constexpr int NWC = CT_TOT / 4;       // 2 or 1 col-halves
    constexpr int NWR = 4 / NWC;          // 2 or 4 row-groups
    constexpr int KT = K / 32;
    constexpr int RPB = NWR * 16;         // rows per block: 32 or 64

    const int wid = threadIdx.x >> 6;
    const int lane = threadIdx.x & 63;
    const int lr = lane & 15;
    const int lg = lane >> 4;
    const int wr = (NWC == 1) ? wid : (wid >> 1);
    const int wc = (NWC == 1) ? 0 : (wid & 1);
    const int row_base = blockIdx.x * RPB + wr * 16;
    const int ct0 = wc * 4;

    f32x4 acc[4];
#pragma unroll
    for (int ct = 0; ct < 4; ct++) acc[ct] = (f32x4){0.f, 0.f, 0.f, 0.f};

    int r = row_base + lr;
    if (r >= M) r = M - 1;  // clamp; result discarded on store

    // ---- A staging ----
    uint4 apk[AF32 ? 1 : KT][2];          // packed path: all kt hoisted
    float4 v0a, v1a;                      // fp32 path: depth-2 rotation
    if (AF32) {
        const float* ap = &Af[(size_t)r * K + lg * 8];
        v0a = *(const float4*)ap;
        v1a = *(const float4*)(ap + 4);
    } else {
        const uint* ab = &Ax[(size_t)r * K + lg * 8];
#pragma unroll
        for (int kt = 0; kt < KT; kt++) {
            apk[kt][0] = *(const uint4*)(ab + kt * 32);
            apk[kt][1] = *(const uint4*)(ab + kt * 32 + 4);
        }
    }

#pragma unroll
    for (int kt = 0; kt < KT; kt++) {
        // B fragments first
        const ushort* bh = &Wph[((size_t)kt * CT_TOT + ct0) * 512 + (size_t)lane * 8];
        const ushort* bl = &Wpl[((size_t)kt * CT_TOT + ct0) * 512 + (size_t)lane * 8];
        bf16x8 bhv[4], blv[4];
#pragma unroll
        for (int ct = 0; ct < 4; ct++) {
            bhv[ct] = *(const bf16x8*)(bh + ct * 512);
            blv[ct] = *(const bf16x8*)(bl + ct * 512);
        }

        // Build current A fragments
        bf16x8 ah, al;
        if (AF32) {
            float4 v0c = v0a, v1c = v1a;
            if (kt + 1 < KT) {
                const float* ap = &Af[(size_t)r * K + (kt + 1) * 32 + lg * 8];
                v0a = *(const float4*)ap;
                v1a = *(const float4*)(ap + 4);
            }
            float av[8] = {v0c.x, v0c.y, v0c.z, v0c.w, v1c.x, v1c.y, v1c.z, v1c.w};
#pragma unroll
            for (int j = 0; j < 8; j++) {
                ushort h = f2bf(av[j]);
                ushort lo = f2bf(av[j] - bf2f(h));
                ah[j] = (short)h;
                al[j] = (short)lo;
            }
        } else {
            union { uint u[4]; bf16x8 v; } ch_, cl_;
#pragma unroll
            for (int j = 0; j < 4; j++) {
                uint u0 = (j < 2) ? ((const uint*)&apk[kt][0])[j * 2]
                                  : ((const uint*)&apk[kt][1])[(j - 2) * 2];
                uint u1 = (j < 2) ? ((const uint*)&apk[kt][0])[j * 2 + 1]
                                  : ((const uint*)&apk[kt][1])[(j - 2) * 2 + 1];
                ch_.u[j] = (u0 >> 16) | (u1 & 0xFFFF0000u);
                cl_.u[j] = (u0 & 0xFFFFu) | (u1 << 16);
            }
            ah = ch_.v;
            al = cl_.v;
        }

#pragma unroll
        for (int ct = 0; ct < 4; ct++) {
            acc[ct] = __builtin_amdgcn_mfma_f32_16x16x32_bf16(ah, bhv[ct], acc[ct], 0, 0, 0);
            acc[ct] = __builtin_amdgcn_mfma_f32_16x16x32_bf16(al, bhv[ct], acc[ct], 0, 0, 0);
            acc[ct] = __builtin_amdgcn_mfma_f32_16x16x32_bf16(ah, blv[ct], acc[ct], 0, 0, 0);
        }
    }

    // Epilogue
    if (OUT_MODE == 2) {
        // slice-major interleaved fp16: wave covers slices (ct0>>1), (ct0>>1)+1
#pragma unroll
        for (int sp = 0; sp < 2; sp++) {
            const int s = (ct0 >> 1) + sp;
            const int cte = sp * 2;
            const int cto = sp * 2 + 1;
#pragma unroll
            for (int j = 0; j < 4; j++) {
                int rr = row_base + lg * 4 + j;
                if (rr >= M) continue;
                float sc = disp[rr];
                f16x2 w;
                w.x = (_Float16)(acc[cte][j] * sc);
                w.y = (_Float16)(acc[cto][j] * sc);
                *(f16x2*)&Ch[(size_t)s * ((size_t)N_NODES * 32) + (size_t)rr * 32 + lr * 2] = w;
            }
        }
    } else {
#pragma unroll
        for (int ct = 0; ct < 4; ct++)
#pragma unroll
            for (int j = 0; j < 4; j++) {
                int rr = row_base + lg * 4 + j;
                if (rr >= M) continue;
                int c = (ct0 + ct) * 16 + lr;
                float v = acc[ct][j];
                if (OUT_MODE == 1) {
                    Cx[(size_t)rr * N + c] = packhl(v + bias[c]);
                } else {
                    Cf[(size_t)rr * N + c] = v + bias[c];
                }
            }
    }
}

// ---------------------------------------------------------------------------
// XCD-sliced CSR aggregation, 4 slices x 32 channels.
// g is slice-major interleaved [4][N][32] fp16 (3.2 MB/slice, L2-resident;
// slice = blockIdx&3 -> XCD pairs via %8 round-robin).
// Wave = one (node, slice): lanes = 4 edge-groups x 16 ch-lanes; one gather
// instruction = 4 edges x 64 B full lines. Unroll-2 -> 8 edges in flight.
// Interleaved pos: lane cl reads f16x2 {ch s*32+cl, ch s*32+16+cl}.
// out = relu(dis[node]*sum + bias) -> packed uint hx row-major (2x 64B lines).
// ---------------------------------------------------------------------------

__global__ __launch_bounds__(256) void aggregate_kernel(const _Float16* __restrict__ g,
                                                        const int* __restrict__ row_ptr,
                                                        const ushort* __restrict__ csr_src,
                                                        const float* __restrict__ dis,
                                                        const float* __restrict__ bias,
                                                        uint* __restrict__ hx) {
    const int slice = blockIdx.x & 3;
    const int nb = blockIdx.x >> 2;
    const int wid = threadIdx.x >> 6;
    const int lane = threadIdx.x & 63;
    const int eg = lane >> 4;     // edge group 0..3
    const int cl = lane & 15;     // channel lane 0..15
    const int node = nb * 4 + wid;
    if (node >= N_NODES) return;
    const _Float16* __restrict__ gs = g + (size_t)slice * ((size_t)N_NODES * 32);

    const int s0 = row_ptr[node];
    const int s1 = row_ptr[node + 1];

    float ax = 0.f, ay = 0.f;
    int e = s0;
    for (; e + 8 <= s1; e += 8) {
        int iA = csr_src[e + eg];
        int iB = csr_src[e + 4 + eg];
        f16x2 vA = *(const f16x2*)&gs[(size_t)iA * 32 + cl * 2];
        f16x2 vB = *(const f16x2*)&gs[(size_t)iB * 32 + cl * 2];
        ax += (float)vA.x + (float)vB.x;
        ay += (float)vA.y + (float)vB.y;
    }
    for (; e < s1; e += 4) {
        int ee = e + eg;
        bool valid = ee < s1;
        int ec = valid ? ee : s0;
        int idx = csr_src[ec];
        f16x2 v = *(const f16x2*)&gs[(size_t)idx * 32 + cl * 2];
        if (valid) {
            ax += (float)v.x;
            ay += (float)v.y;
        }
    }
    // Fold 4 edge-groups (lane bits 4,5)
    ax += __shfl_xor(ax, 16);
    ay += __shfl_xor(ay, 16);
    ax += __shfl_xor(ax, 32);
    ay += __shfl_xor(ay, 32);

    if (eg == 0) {
        const float dn = dis[node];
        const int c1 = slice * 32 + cl;
        const int c2 = c1 + 16;
        float vx = fmaxf(dn * ax + bias[c1], 0.f);
        float vy = fmaxf(dn * ay + bias[c2], 0.f);
        hx[(size_t)node * HID_C + c1] = packhl(vx);
        hx[(size_t)node * HID_C + c2] = packhl(vy);
    }
}

// ---------------------------------------------------------------------------
// Launch
// ---------------------------------------------------------------------------

extern "C" void kernel_launch(void* const* d_in, const int* in_sizes, int n_in,
                              void* d_out, int out_size, void* d_ws, size_t ws_size,
                              hipStream_t stream) {
    const float* x       = (const float*)d_in[0];
    const int*   eidx    = (const int*)d_in[1];
    const float* proj_W  = (const float*)d_in[2];
    const float* proj_b  = (const float*)d_in[3];
    const float* conv_W0 = (const float*)d_in[4];
    const float* conv_b0 = (const float*)d_in[5];
    const float* conv_W1 = (const float*)d_in[6];
    const float* conv_b1 = (const float*)d_in[7];
    const float* conv_W2 = (const float*)d_in[8];
    const float* conv_b2 = (const float*)d_in[9];
    const float* out_W   = (const float*)d_in[10];
    const float* out_b   = (const float*)d_in[11];
    float* out = (float*)d_out;

    const int* src = eidx;
    const int* dst = eidx + N_EDGES;

    char* ws = (char*)d_ws;
    size_t off = 0;
    auto carve = [&](size_t bytes) {
        void* p = ws + off;
        off += (bytes + 255) & ~(size_t)255;
        return p;
    };
    int*    degi     = (int*)carve(N_NODES * sizeof(int));
    int*    row_ptr  = (int*)carve((N_NODES + 1) * sizeof(int));
    int*    cursor   = (int*)carve(N_NODES * sizeof(int));
    ushort* csr_src  = (ushort*)carve((size_t)N_TOT * sizeof(ushort));
    uint*   binned   = (uint*)carve((size_t)N_TOT * sizeof(uint));
    int*    bincur   = (int*)carve(N_BINS * sizeof(int));
    float*  dis      = (float*)carve(N_NODES * sizeof(float));
    int*    partials = (int*)carve(NB_SCAN * sizeof(int));
    int*    poff     = (int*)carve(NB_SCAN * sizeof(int));
    ushort* projPh = (ushort*)carve((size_t)IN_C * HID_C * sizeof(ushort));
    ushort* projPl = (ushort*)carve((size_t)IN_C * HID_C * sizeof(ushort));
    ushort* convPh[3], *convPl[3];
    for (int l = 0; l < 3; l++) {
        convPh[l] = (ushort*)carve((size_t)HID_C * HID_C * sizeof(ushort));
        convPl[l] = (ushort*)carve((size_t)HID_C * HID_C * sizeof(ushort));
    }
    ushort* outPh = (ushort*)carve((size_t)HID_C * OUT_C * sizeof(ushort));
    ushort* outPl = (ushort*)carve((size_t)HID_C * OUT_C * sizeof(ushort));
    uint*   hx = (uint*)carve((size_t)N_NODES * HID_C * sizeof(uint));       // packed hi/lo
    _Float16* g = (_Float16*)carve((size_t)N_NODES * HID_C * sizeof(_Float16)); // [4][N][32]

    // Graph preprocessing
    init_deg_kernel<<<NB_SCAN, 256, 0, stream>>>(degi, bincur);
    count_deg_kernel<<<(N_EDGES + 255) / 256, 256, 0, stream>>>(dst, degi);
    deg_partial_kernel<<<NB_SCAN, 256, 0, stream>>>(degi, partials);
    scan_partials_kernel<<<1, 256, 0, stream>>>(partials, poff, row_ptr);
    scan_final_kernel<<<NB_SCAN, 256, 0, stream>>>(degi, poff, row_ptr, cursor, dis);
    bin_scatter_kernel<<<RB_GRID, RB_BLOCK, 0, stream>>>(
        src, dst, row_ptr, bincur, binned);
    csr_scatter_kernel<<<(N_TOT + 255) / 256, 256, 0, stream>>>(
        binned, cursor, csr_src);

    // Weight packing
    pack_w_kernel<<<(IN_C / 32) * (HID_C / 16), 64, 0, stream>>>(proj_W, projPh, projPl, IN_C, HID_C);
    pack_w_kernel<<<(HID_C / 32) * (HID_C / 16), 64, 0, stream>>>(conv_W0, convPh[0], convPl[0], HID_C, HID_C);
    pack_w_kernel<<<(HID_C / 32) * (HID_C / 16), 64, 0, stream>>>(conv_W1, convPh[1], convPl[1], HID_C, HID_C);
    pack_w_kernel<<<(HID_C / 32) * (HID_C / 16), 64, 0, stream>>>(conv_W2, convPh[2], convPl[2], HID_C, HID_C);
    pack_w_kernel<<<(HID_C / 32) * (OUT_C / 16), 64, 0, stream>>>(out_W, outPh, outPl, HID_C, OUT_C);

    const int grid_n128 = (N_NODES + 31) / 32;   // 1563 (N=128 kernels)
    const int grid_n64  = (N_NODES + 63) / 64;   // 782  (N=64 kernel)
    const int agg_grid  = ((N_NODES + 3) / 4) * 4;  // 50000: (node-group) x 4 slices

    // Projection: hx = pack(x @ proj_W + proj_b)
    gemm_mfma_kernel<IN_C, HID_C, 1, true><<<grid_n128, 256, 0, stream>>>(
        x, nullptr, projPh, projPl, proj_b, nullptr, nullptr, hx, nullptr, N_NODES);

    // 3 GCN layers
    ushort* Wh_[3] = {convPh[0], convPh[1], convPh[2]};
    ushort* Wl_[3] = {convPl[0], convPl[1], convPl[2]};
    const float* bs_[3] = {conv_b0, conv_b1, conv_b2};
    for (int l = 0; l < 3; l++) {
        // g[slice][node][32] = fp16(dis[node] * (h @ W)[node]) interleaved
        gemm_mfma_kernel<HID_C, HID_C, 2, false><<<grid_n128, 256, 0, stream>>>(
            nullptr, hx, Wh_[l], Wl_[l], nullptr, dis, nullptr, nullptr, g, N_NODES);
        aggregate_kernel<<<agg_grid, 256, 0, stream>>>(
            g, row_ptr, csr_src, dis, bs_[l], hx);
    }

    // Output: out = h @ out_W + out_b (fp32)
    gemm_mfma_kernel<HID_C, OUT_C, 0, false><<<grid_n64, 256, 0, stream>>>(
        nullptr, hx, outPh, outPl, out_b, nullptr, out, nullptr, nullptr, N_NODES);
}

// Round 13
// 322.691 us; speedup vs baseline: 1.3009x; 1.3009x over previous
//
#include <hip/hip_runtime.h>
#include <hip/hip_bf16.h>

// Problem constants (match reference)
#define N_NODES 50000
#define N_EDGES 800000
#define IN_C 256
#define HID_C 128
#define OUT_C 64

#define NB_SCAN ((N_NODES + 255) / 256)   // 196 blocks of 256 nodes
#define N_BINS ((N_NODES + 127) / 128)    // 391 dst-bins of 128 nodes

// Radix binning pass
#define RB_BLOCK 1024
#define RB_EPT 8
#define RB_CHUNK (RB_BLOCK * RB_EPT)      // 8192 edges per block
#define N_TOT (N_EDGES + N_NODES)         // 850000
#define RB_GRID ((N_TOT + RB_CHUNK - 1) / RB_CHUNK)  // 104

typedef __attribute__((ext_vector_type(8))) short bf16x8;
typedef __attribute__((ext_vector_type(4))) float f32x4;
typedef __attribute__((ext_vector_type(2))) _Float16 f16x2;

__device__ __forceinline__ ushort f2bf(float f) {
    uint u = __float_as_uint(f);
    u += 0x7fff + ((u >> 16) & 1);   // round-to-nearest-even
    return (ushort)(u >> 16);
}
__device__ __forceinline__ float bf2f(ushort h) {
    return __uint_as_float(((uint)h) << 16);
}
// Pack one fp32 value into uint: bf16(hi)<<16 | bf16(residual lo)
__device__ __forceinline__ uint packhl(float v) {
    ushort h = f2bf(v);
    ushort l = f2bf(v - bf2f(h));
    return ((uint)h << 16) | (uint)l;
}

// ---------------------------------------------------------------------------
// Graph preprocessing
// ---------------------------------------------------------------------------

__global__ __launch_bounds__(256) void init_deg_kernel(int* __restrict__ degi,
                                                       int* __restrict__ bincur) {
    int i = blockIdx.x * 256 + threadIdx.x;
    if (i < N_NODES) degi[i] = 1;  // self-loop
    if (i < N_BINS) bincur[i] = 0;
}

__global__ __launch_bounds__(256) void count_deg_kernel(const int* __restrict__ dst,
                                                        int* __restrict__ degi) {
    int e = blockIdx.x * 256 + threadIdx.x;
    if (e < N_EDGES) atomicAdd(&degi[dst[e]], 1);
}

__global__ __launch_bounds__(256) void deg_partial_kernel(const int* __restrict__ degi,
                                                          int* __restrict__ partials) {
    __shared__ int s[256];
    int t = threadIdx.x;
    int i = blockIdx.x * 256 + t;
    s[t] = (i < N_NODES) ? degi[i] : 0;
    __syncthreads();
#pragma unroll
    for (int off = 128; off > 0; off >>= 1) {
        if (t < off) s[t] += s[t + off];
        __syncthreads();
    }
    if (t == 0) partials[blockIdx.x] = s[0];
}

__global__ __launch_bounds__(256) void scan_partials_kernel(const int* __restrict__ partials,
                                                            int* __restrict__ partial_off,
                                                            int* __restrict__ row_ptr) {
    __shared__ int s[256];
    int t = threadIdx.x;
    s[t] = (t < NB_SCAN) ? partials[t] : 0;
    __syncthreads();
#pragma unroll
    for (int off = 1; off < 256; off <<= 1) {
        int x = s[t];
        int add = (t >= off) ? s[t - off] : 0;
        __syncthreads();
        s[t] = x + add;
        __syncthreads();
    }
    if (t < NB_SCAN) partial_off[t] = (t == 0) ? 0 : s[t - 1];
    if (t == 255) row_ptr[N_NODES] = s[255];
}

__global__ __launch_bounds__(256) void scan_final_kernel(const int* __restrict__ degi,
                                                         const int* __restrict__ partial_off,
                                                         int* __restrict__ row_ptr,
                                                         int* __restrict__ cursor,
                                                         float* __restrict__ dis) {
    __shared__ int s[256];
    int t = threadIdx.x;
    int i = blockIdx.x * 256 + t;
    int d = (i < N_NODES) ? degi[i] : 0;
    s[t] = d;
    __syncthreads();
#pragma unroll
    for (int off = 1; off < 256; off <<= 1) {
        int x = s[t];
        int add = (t >= off) ? s[t - off] : 0;
        __syncthreads();
        s[t] = x + add;
        __syncthreads();
    }
    if (i < N_NODES) {
        int excl = partial_off[blockIdx.x] + s[t] - d;
        row_ptr[i] = excl;
        cursor[i] = excl;
        dis[i] = rsqrtf((float)d);
    }
}

// ---------------------------------------------------------------------------
// Two-pass binned CSR build, pass 1 = block-local LDS radix scatter.
// ---------------------------------------------------------------------------

__global__ __launch_bounds__(RB_BLOCK) void bin_scatter_kernel(
    const int* __restrict__ src, const int* __restrict__ dst,
    const int* __restrict__ row_ptr, int* __restrict__ bincur,
    uint* __restrict__ binned) {
    __shared__ int hist[N_BINS];
    __shared__ int cur[N_BINS];
    const int t = threadIdx.x;
    for (int b = t; b < N_BINS; b += RB_BLOCK) hist[b] = 0;
    __syncthreads();

    uint pk[RB_EPT];
    int bn[RB_EPT];
    const int base = blockIdx.x * RB_CHUNK;
#pragma unroll
    for (int k = 0; k < RB_EPT; k++) {
        int i = base + k * RB_BLOCK + t;
        bn[k] = -1;
        if (i < N_TOT) {
            int s, d;
            if (i < N_EDGES) {
                s = src[i];
                d = dst[i];
            } else {
                s = d = i - N_EDGES;
            }
            pk[k] = (uint)s | ((uint)d << 16);
            bn[k] = d >> 7;
            atomicAdd(&hist[bn[k]], 1);
        }
    }
    __syncthreads();

    for (int b = t; b < N_BINS; b += RB_BLOCK) {
        int c = hist[b];
        int g0 = (c > 0) ? atomicAdd(&bincur[b], c) : 0;
        cur[b] = row_ptr[b << 7] + g0;
    }
    __syncthreads();

#pragma unroll
    for (int k = 0; k < RB_EPT; k++) {
        if (bn[k] >= 0) {
            int pos = atomicAdd(&cur[bn[k]], 1);
            binned[pos] = pk[k];
        }
    }
}

// Pass 2: stream bins sequentially; csr slot lands in the bin's contiguous
// ~9 KB region (localized writes). csr_src is ushort (src < 65536).
__global__ __launch_bounds__(256) void csr_scatter_kernel(const uint* __restrict__ binned,
                                                          int* __restrict__ cursor,
                                                          ushort* __restrict__ csr_src) {
    int i = blockIdx.x * 256 + threadIdx.x;
    if (i >= N_TOT) return;
    uint e = binned[i];
    int s = (int)(e & 0xFFFFu);
    int d = (int)(e >> 16);
    int slot = atomicAdd(&cursor[d], 1);
    csr_src[slot] = (ushort)s;
}

// ---------------------------------------------------------------------------
// Weight packing: W[K][N] fp32 -> fragment-ordered bf16 hi/lo
// ---------------------------------------------------------------------------

__global__ __launch_bounds__(64) void pack_w_kernel(const float* __restrict__ W,
                                                    ushort* __restrict__ Ph,
                                                    ushort* __restrict__ Pl,
                                                    int K, int N) {
    int lane = threadIdx.x;
    int CT = N / 16;
    int ct = blockIdx.x % CT;
    int kt = blockIdx.x / CT;
    int lr = lane & 15, lg = lane >> 4;
    size_t base = ((size_t)blockIdx.x * 64 + lane) * 8;
#pragma unroll
    for (int j = 0; j < 8; j++) {
        float w = W[(size_t)(kt * 32 + lg * 8 + j) * N + ct * 16 + lr];
        ushort h = f2bf(w);
        ushort lo = f2bf(w - bf2f(h));
        Ph[base + j] = h;
        Pl[base + j] = lo;
    }
}

// ---------------------------------------------------------------------------
// LDS-free MFMA GEMM, 3-term bf16 split, packed activations, MT=2 m-tiles
// per wave (32 rows/wave): halves wave count, doubles A-load MLP, amortizes
// each B-fragment load over 24 MFMAs.
// N=128: block = 4 waves = 2 row-groups x 2 col-halves = 64 rows, grid 782.
// N=64:  block = 4 row-groups = 128 rows, grid 391.
// OUT_MODE: 0 = fp32 + bias, 1 = packed uint + bias, 2 = fp16 * dis[row]
// ---------------------------------------------------------------------------

template <int K, int N, int OUT_MODE, bool AF32>
__global__ __launch_bounds__(256) void gemm_mfma_kernel(
    const float* __restrict__ Af, const uint* __restrict__ Ax,
    const ushort* __restrict__ Wph, const ushort* __restrict__ Wpl,
    const float* __restrict__ bias, const float* __restrict__ disp,
    float* __restrict__ Cf, uint* __restrict__ Cx, _Float16* __restrict__ Ch,
    int M) {
    constexpr int CT_TOT = N / 16;        // 8 (N=128) or 4 (N=64)
    constexpr int NWC = CT_TOT / 4;       // 2 or 1 col-halves
    constexpr int NWR = 4 / NWC;          // 2 or 4 row-groups
    constexpr int KT = K / 32;
    constexpr int MT = 2;                 // m-tiles per wave
    constexpr int RPB = NWR * MT * 16;    // rows per block: 64 or 128

    const int wid = threadIdx.x >> 6;
    const int lane = threadIdx.x & 63;
    const int lr = lane & 15;
    const int lg = lane >> 4;
    const int wr = (NWC == 1) ? wid : (wid >> 1);
    const int wc = (NWC == 1) ? 0 : (wid & 1);
    const int row_base = blockIdx.x * RPB + wr * (MT * 16);
    const int ct0 = wc * 4;

    f32x4 acc[MT][4];
#pragma unroll
    for (int mt = 0; mt < MT; mt++)
#pragma unroll
        for (int ct = 0; ct < 4; ct++) acc[mt][ct] = (f32x4){0.f, 0.f, 0.f, 0.f};

    int rr_[MT];
#pragma unroll
    for (int mt = 0; mt < MT; mt++) {
        int r = row_base + mt * 16 + lr;
        rr_[mt] = (r >= M) ? (M - 1) : r;  // clamp; result discarded on store
    }

    // ---- A staging ----
    uint4 apk[AF32 ? 1 : KT][MT][2];      // packed path: ALL kt hoisted (max MLP)
    float4 v0a[MT], v1a[MT];              // fp32 path: depth-2 rotation per mt
    if (AF32) {
#pragma unroll
        for (int mt = 0; mt < MT; mt++) {
            const float* ap = &Af[(size_t)rr_[mt] * K + lg * 8];
            v0a[mt] = *(const float4*)ap;
            v1a[mt] = *(const float4*)(ap + 4);
        }
    } else {
#pragma unroll
        for (int kt = 0; kt < KT; kt++)
#pragma unroll
            for (int mt = 0; mt < MT; mt++) {
                const uint* ab = &Ax[(size_t)rr_[mt] * K + lg * 8];
                apk[kt][mt][0] = *(const uint4*)(ab + kt * 32);
                apk[kt][mt][1] = *(const uint4*)(ab + kt * 32 + 4);
            }
    }

#pragma unroll
    for (int kt = 0; kt < KT; kt++) {
        // B fragments first
        const ushort* bh = &Wph[((size_t)kt * CT_TOT + ct0) * 512 + (size_t)lane * 8];
        const ushort* bl = &Wpl[((size_t)kt * CT_TOT + ct0) * 512 + (size_t)lane * 8];
        bf16x8 bhv[4], blv[4];
#pragma unroll
        for (int ct = 0; ct < 4; ct++) {
            bhv[ct] = *(const bf16x8*)(bh + ct * 512);
            blv[ct] = *(const bf16x8*)(bl + ct * 512);
        }

        // Build current A fragments per m-tile
        bf16x8 ah[MT], al[MT];
#pragma unroll
        for (int mt = 0; mt < MT; mt++) {
            if (AF32) {
                float4 v0c = v0a[mt], v1c = v1a[mt];
                if (kt + 1 < KT) {  // issue next-kt A AFTER this kt's B loads
                    const float* ap = &Af[(size_t)rr_[mt] * K + (kt + 1) * 32 + lg * 8];
                    v0a[mt] = *(const float4*)ap;
                    v1a[mt] = *(const float4*)(ap + 4);
                }
                float av[8] = {v0c.x, v0c.y, v0c.z, v0c.w, v1c.x, v1c.y, v1c.z, v1c.w};
#pragma unroll
                for (int j = 0; j < 8; j++) {
                    ushort h = f2bf(av[j]);
                    ushort lo = f2bf(av[j] - bf2f(h));
                    ah[mt][j] = (short)h;
                    al[mt][j] = (short)lo;
                }
            } else {
                union { uint u[4]; bf16x8 v; } ch_, cl_;
#pragma unroll
                for (int j = 0; j < 4; j++) {
                    uint u0 = (j < 2) ? ((const uint*)&apk[kt][mt][0])[j * 2]
                                      : ((const uint*)&apk[kt][mt][1])[(j - 2) * 2];
                    uint u1 = (j < 2) ? ((const uint*)&apk[kt][mt][0])[j * 2 + 1]
                                      : ((const uint*)&apk[kt][mt][1])[(j - 2) * 2 + 1];
                    ch_.u[j] = (u0 >> 16) | (u1 & 0xFFFF0000u);
                    cl_.u[j] = (u0 & 0xFFFFu) | (u1 << 16);
                }
                ah[mt] = ch_.v;
                al[mt] = cl_.v;
            }
        }

#pragma unroll
        for (int mt = 0; mt < MT; mt++)
#pragma unroll
            for (int ct = 0; ct < 4; ct++) {
                acc[mt][ct] = __builtin_amdgcn_mfma_f32_16x16x32_bf16(ah[mt], bhv[ct], acc[mt][ct], 0, 0, 0);
                acc[mt][ct] = __builtin_amdgcn_mfma_f32_16x16x32_bf16(al[mt], bhv[ct], acc[mt][ct], 0, 0, 0);
                acc[mt][ct] = __builtin_amdgcn_mfma_f32_16x16x32_bf16(ah[mt], blv[ct], acc[mt][ct], 0, 0, 0);
            }
    }

    // Epilogue: D[row][col], row = mt*16 + lg*4 + j, col = (ct0+ct)*16 + lr
#pragma unroll
    for (int mt = 0; mt < MT; mt++)
#pragma unroll
        for (int ct = 0; ct < 4; ct++)
#pragma unroll
            for (int j = 0; j < 4; j++) {
                int rr = row_base + mt * 16 + lg * 4 + j;
                if (rr >= M) continue;
                int c = (ct0 + ct) * 16 + lr;
                float v = acc[mt][ct][j];
                if (OUT_MODE == 2) {
                    Ch[(size_t)rr * N + c] = (_Float16)(v * disp[rr]);
                } else if (OUT_MODE == 1) {
                    Cx[(size_t)rr * N + c] = packhl(v + bias[c]);
                } else {
                    Cf[(size_t)rr * N + c] = v + bias[c];
                }
            }
}

// ---------------------------------------------------------------------------
// CSR aggregation (r11 proven shape): wave = node, 64 lanes x f16x2 = full
// 128-ch fp16 row (256 B) per instruction, unroll-8 (deep MLP).
// g pre-scaled by dis[src] in GEMM epilogue.
// out = relu(dis[node]*sum + bias) -> packed uint (uint2/lane, 512 B/wave).
// ---------------------------------------------------------------------------

__global__ __launch_bounds__(256) void aggregate_kernel(const _Float16* __restrict__ g,
                                                        const int* __restrict__ row_ptr,
                                                        const ushort* __restrict__ csr_src,
                                                        const float* __restrict__ dis,
                                                        const float* __restrict__ bias,
                                                        uint* __restrict__ hx) {
    const int wid = threadIdx.x >> 6;
    const int lane = threadIdx.x & 63;
    const int node = blockIdx.x * 4 + wid;
    if (node >= N_NODES) return;
    const int c2 = lane * 2;

    const int s0 = row_ptr[node];
    const int s1 = row_ptr[node + 1];

    float ax = 0.f, ay = 0.f;
    int e = s0;
    for (; e + 8 <= s1; e += 8) {
        int i0 = csr_src[e + 0];
        int i1 = csr_src[e + 1];
        int i2 = csr_src[e + 2];
        int i3 = csr_src[e + 3];
        int i4 = csr_src[e + 4];
        int i5 = csr_src[e + 5];
        int i6 = csr_src[e + 6];
        int i7 = csr_src[e + 7];
        f16x2 v0 = *(const f16x2*)&g[(size_t)i0 * HID_C + c2];
        f16x2 v1 = *(const f16x2*)&g[(size_t)i1 * HID_C + c2];
        f16x2 v2 = *(const f16x2*)&g[(size_t)i2 * HID_C + c2];
        f16x2 v3 = *(const f16x2*)&g[(size_t)i3 * HID_C + c2];
        f16x2 v4 = *(const f16x2*)&g[(size_t)i4 * HID_C + c2];
        f16x2 v5 = *(const f16x2*)&g[(size_t)i5 * HID_C + c2];
        f16x2 v6 = *(const f16x2*)&g[(size_t)i6 * HID_C + c2];
        f16x2 v7 = *(const f16x2*)&g[(size_t)i7 * HID_C + c2];
        ax += (((float)v0.x + (float)v1.x) + ((float)v2.x + (float)v3.x)) +
              (((float)v4.x + (float)v5.x) + ((float)v6.x + (float)v7.x));
        ay += (((float)v0.y + (float)v1.y) + ((float)v2.y + (float)v3.y)) +
              (((float)v4.y + (float)v5.y) + ((float)v6.y + (float)v7.y));
    }
    for (; e < s1; e++) {
        int i0 = csr_src[e];
        f16x2 v0 = *(const f16x2*)&g[(size_t)i0 * HID_C + c2];
        ax += (float)v0.x;
        ay += (float)v0.y;
    }

    const float dn = dis[node];
    float2 bb = *(const float2*)&bias[c2];
    float vx = fmaxf(dn * ax + bb.x, 0.f);
    float vy = fmaxf(dn * ay + bb.y, 0.f);
    uint2 w;
    w.x = packhl(vx);
    w.y = packhl(vy);
    *(uint2*)&hx[(size_t)node * HID_C + c2] = w;
}

// ---------------------------------------------------------------------------
// Launch
// ---------------------------------------------------------------------------

extern "C" void kernel_launch(void* const* d_in, const int* in_sizes, int n_in,
                              void* d_out, int out_size, void* d_ws, size_t ws_size,
                              hipStream_t stream) {
    const float* x       = (const float*)d_in[0];
    const int*   eidx    = (const int*)d_in[1];
    const float* proj_W  = (const float*)d_in[2];
    const float* proj_b  = (const float*)d_in[3];
    const float* conv_W0 = (const float*)d_in[4];
    const float* conv_b0 = (const float*)d_in[5];
    const float* conv_W1 = (const float*)d_in[6];
    const float* conv_b1 = (const float*)d_in[7];
    const float* conv_W2 = (const float*)d_in[8];
    const float* conv_b2 = (const float*)d_in[9];
    const float* out_W   = (const float*)d_in[10];
    const float* out_b   = (const float*)d_in[11];
    float* out = (float*)d_out;

    const int* src = eidx;
    const int* dst = eidx + N_EDGES;

    char* ws = (char*)d_ws;
    size_t off = 0;
    auto carve = [&](size_t bytes) {
        void* p = ws + off;
        off += (bytes + 255) & ~(size_t)255;
        return p;
    };
    int*    degi     = (int*)carve(N_NODES * sizeof(int));
    int*    row_ptr  = (int*)carve((N_NODES + 1) * sizeof(int));
    int*    cursor   = (int*)carve(N_NODES * sizeof(int));
    ushort* csr_src  = (ushort*)carve((size_t)N_TOT * sizeof(ushort));
    uint*   binned   = (uint*)carve((size_t)N_TOT * sizeof(uint));
    int*    bincur   = (int*)carve(N_BINS * sizeof(int));
    float*  dis      = (float*)carve(N_NODES * sizeof(float));
    int*    partials = (int*)carve(NB_SCAN * sizeof(int));
    int*    poff     = (int*)carve(NB_SCAN * sizeof(int));
    ushort* projPh = (ushort*)carve((size_t)IN_C * HID_C * sizeof(ushort));
    ushort* projPl = (ushort*)carve((size_t)IN_C * HID_C * sizeof(ushort));
    ushort* convPh[3], *convPl[3];
    for (int l = 0; l < 3; l++) {
        convPh[l] = (ushort*)carve((size_t)HID_C * HID_C * sizeof(ushort));
        convPl[l] = (ushort*)carve((size_t)HID_C * HID_C * sizeof(ushort));
    }
    ushort* outPh = (ushort*)carve((size_t)HID_C * OUT_C * sizeof(ushort));
    ushort* outPl = (ushort*)carve((size_t)HID_C * OUT_C * sizeof(ushort));
    uint*   hx = (uint*)carve((size_t)N_NODES * HID_C * sizeof(uint));       // packed hi/lo
    _Float16* g = (_Float16*)carve((size_t)N_NODES * HID_C * sizeof(_Float16)); // row-major fp16

    // Graph preprocessing
    init_deg_kernel<<<NB_SCAN, 256, 0, stream>>>(degi, bincur);
    count_deg_kernel<<<(N_EDGES + 255) / 256, 256, 0, stream>>>(dst, degi);
    deg_partial_kernel<<<NB_SCAN, 256, 0, stream>>>(degi, partials);
    scan_partials_kernel<<<1, 256, 0, stream>>>(partials, poff, row_ptr);
    scan_final_kernel<<<NB_SCAN, 256, 0, stream>>>(degi, poff, row_ptr, cursor, dis);
    bin_scatter_kernel<<<RB_GRID, RB_BLOCK, 0, stream>>>(
        src, dst, row_ptr, bincur, binned);
    csr_scatter_kernel<<<(N_TOT + 255) / 256, 256, 0, stream>>>(
        binned, cursor, csr_src);

    // Weight packing
    pack_w_kernel<<<(IN_C / 32) * (HID_C / 16), 64, 0, stream>>>(proj_W, projPh, projPl, IN_C, HID_C);
    pack_w_kernel<<<(HID_C / 32) * (HID_C / 16), 64, 0, stream>>>(conv_W0, convPh[0], convPl[0], HID_C, HID_C);
    pack_w_kernel<<<(HID_C / 32) * (HID_C / 16), 64, 0, stream>>>(conv_W1, convPh[1], convPl[1], HID_C, HID_C);
    pack_w_kernel<<<(HID_C / 32) * (HID_C / 16), 64, 0, stream>>>(conv_W2, convPh[2], convPl[2], HID_C, HID_C);
    pack_w_kernel<<<(HID_C / 32) * (OUT_C / 16), 64, 0, stream>>>(out_W, outPh, outPl, HID_C, OUT_C);

    const int grid_n128 = (N_NODES + 63) / 64;    // 782  (N=128 kernels, 64 rows/block)
    const int grid_n64  = (N_NODES + 127) / 128;  // 391  (N=64 kernel, 128 rows/block)
    const int agg_grid  = (N_NODES + 3) / 4;      // 12500

    // Projection: hx = pack(x @ proj_W + proj_b)
    gemm_mfma_kernel<IN_C, HID_C, 1, true><<<grid_n128, 256, 0, stream>>>(
        x, nullptr, projPh, projPl, proj_b, nullptr, nullptr, hx, nullptr, N_NODES);

    // 3 GCN layers
    ushort* Wh_[3] = {convPh[0], convPh[1], convPh[2]};
    ushort* Wl_[3] = {convPl[0], convPl[1], convPl[2]};
    const float* bs_[3] = {conv_b0, conv_b1, conv_b2};
    for (int l = 0; l < 3; l++) {
        // g[node][128] = fp16(dis[node] * (h @ W)[node])
        gemm_mfma_kernel<HID_C, HID_C, 2, false><<<grid_n128, 256, 0, stream>>>(
            nullptr, hx, Wh_[l], Wl_[l], nullptr, dis, nullptr, nullptr, g, N_NODES);
        aggregate_kernel<<<agg_grid, 256, 0, stream>>>(
            g, row_ptr, csr_src, dis, bs_[l], hx);
    }

    // Output: out = h @ out_W + out_b (fp32)
    gemm_mfma_kernel<HID_C, OUT_C, 0, false><<<grid_n64, 256, 0, stream>>>(
        nullptr, hx, outPh, outPl, out_b, nullptr, out, nullptr, nullptr, N_NODES);
}

// Round 14
// 257.647 us; speedup vs baseline: 1.6293x; 1.2525x over previous
//
#include <hip/hip_runtime.h>
#include <hip/hip_bf16.h>

// Problem constants (match reference)
#define N_NODES 50000
#define N_EDGES 800000
#define IN_C 256
#define HID_C 128
#define OUT_C 64

#define N_BINS ((N_NODES + 127) / 128)    // 391 dst-bins of 128 nodes
#define N_TOT (N_EDGES + N_NODES)         // 850000

// Radix binning pass
#define RB_BLOCK 1024
#define RB_EPT 8
#define RB_CHUNK (RB_BLOCK * RB_EPT)      // 8192 edges per block
#define RB_GRID ((N_TOT + RB_CHUNK - 1) / RB_CHUNK)  // 104

typedef __attribute__((ext_vector_type(8))) short bf16x8;
typedef __attribute__((ext_vector_type(4))) float f32x4;
typedef __attribute__((ext_vector_type(2))) _Float16 f16x2;

__device__ __forceinline__ ushort f2bf(float f) {
    uint u = __float_as_uint(f);
    u += 0x7fff + ((u >> 16) & 1);   // round-to-nearest-even
    return (ushort)(u >> 16);
}
__device__ __forceinline__ float bf2f(ushort h) {
    return __uint_as_float(((uint)h) << 16);
}
// Pack one fp32 value into uint: bf16(hi)<<16 | bf16(residual lo)
__device__ __forceinline__ uint packhl(float v) {
    ushort h = f2bf(v);
    ushort l = f2bf(v - bf2f(h));
    return ((uint)h << 16) | (uint)l;
}

// ---------------------------------------------------------------------------
// Graph preprocessing (bin-centric, no per-node global atomics)
// ---------------------------------------------------------------------------

__global__ __launch_bounds__(256) void zero_binhist_kernel(int* __restrict__ binhist) {
    int i = blockIdx.x * 256 + threadIdx.x;
    if (i < N_BINS) binhist[i] = 0;
}

// LDS histogram over 391 bins, one global add per (block,bin)
__global__ __launch_bounds__(256) void bin_hist_kernel(const int* __restrict__ dst,
                                                       int* __restrict__ binhist) {
    __shared__ int h[N_BINS];
    int t = threadIdx.x;
    for (int b = t; b < N_BINS; b += 256) h[b] = 0;
    __syncthreads();
    for (int i = blockIdx.x * 256 + t; i < N_EDGES; i += gridDim.x * 256)
        atomicAdd(&h[dst[i] >> 7], 1);
    __syncthreads();
    for (int b = t; b < N_BINS; b += 256)
        if (h[b]) atomicAdd(&binhist[b], h[b]);
}

// One block: scan bins (self-loops added analytically), zero bincur,
// write bin_base[0..N_BINS] and row_ptr[N_NODES].
__global__ __launch_bounds__(512) void bin_scan_kernel(const int* __restrict__ binhist,
                                                       int* __restrict__ bin_base,
                                                       int* __restrict__ bincur,
                                                       int* __restrict__ row_ptr) {
    __shared__ int s[512];
    int t = threadIdx.x;
    int v = 0;
    if (t < N_BINS) {
        int sl = (t == N_BINS - 1) ? (N_NODES - (N_BINS - 1) * 128) : 128;
        v = binhist[t] + sl;
    }
    s[t] = v;
    __syncthreads();
    for (int off = 1; off < 512; off <<= 1) {
        int x = s[t];
        int a = (t >= off) ? s[t - off] : 0;
        __syncthreads();
        s[t] = x + a;
        __syncthreads();
    }
    if (t < N_BINS) {
        bin_base[t] = s[t] - v;
        bincur[t] = 0;
    }
    if (t == N_BINS - 1) bin_base[N_BINS] = s[t];
    if (t == 0) row_ptr[N_NODES] = N_TOT;
}

// Pass 1: block-local LDS radix scatter into dst-bins.
__global__ __launch_bounds__(RB_BLOCK) void bin_scatter_kernel(
    const int* __restrict__ src, const int* __restrict__ dst,
    const int* __restrict__ bin_base, int* __restrict__ bincur,
    uint* __restrict__ binned) {
    __shared__ int hist[N_BINS];
    __shared__ int cur[N_BINS];
    const int t = threadIdx.x;
    for (int b = t; b < N_BINS; b += RB_BLOCK) hist[b] = 0;
    __syncthreads();

    uint pk[RB_EPT];
    int bn[RB_EPT];
    const int base = blockIdx.x * RB_CHUNK;
#pragma unroll
    for (int k = 0; k < RB_EPT; k++) {
        int i = base + k * RB_BLOCK + t;
        bn[k] = -1;
        if (i < N_TOT) {
            int s, d;
            if (i < N_EDGES) {
                s = src[i];
                d = dst[i];
            } else {
                s = d = i - N_EDGES;
            }
            pk[k] = (uint)s | ((uint)d << 16);
            bn[k] = d >> 7;
            atomicAdd(&hist[bn[k]], 1);
        }
    }
    __syncthreads();

    for (int b = t; b < N_BINS; b += RB_BLOCK) {
        int c = hist[b];
        int g0 = (c > 0) ? atomicAdd(&bincur[b], c) : 0;
        cur[b] = bin_base[b] + g0;
    }
    __syncthreads();

#pragma unroll
    for (int k = 0; k < RB_EPT; k++) {
        if (bn[k] >= 0) {
            int pos = atomicAdd(&cur[bn[k]], 1);
            binned[pos] = pk[k];
        }
    }
}

// Pass 2: one block per bin. LDS 128-node histogram + scan -> row_ptr, dis,
// and csr_src (LDS atomics only, bin-local writes).
__global__ __launch_bounds__(256) void csr_build_kernel(const uint* __restrict__ binned,
                                                        const int* __restrict__ bin_base,
                                                        int* __restrict__ row_ptr,
                                                        float* __restrict__ dis,
                                                        ushort* __restrict__ csr_src) {
    __shared__ int hist[128];
    __shared__ int sc[256];
    __shared__ int exs[128];
    __shared__ int cur[128];
    const int b = blockIdx.x;
    const int t = threadIdx.x;
    const int start = bin_base[b];
    const int cnt = bin_base[b + 1] - start;
    const int nloc = min(128, N_NODES - b * 128);

    if (t < 128) hist[t] = 0;
    __syncthreads();
    for (int i = t; i < cnt; i += 256) {
        uint e = binned[start + i];
        atomicAdd(&hist[(e >> 16) & 127], 1);
    }
    __syncthreads();
    sc[t] = (t < 128) ? hist[t] : 0;
    __syncthreads();
    for (int off = 1; off < 128; off <<= 1) {
        int x = sc[t];
        int a = (t >= off) ? sc[t - off] : 0;
        __syncthreads();
        sc[t] = x + a;
        __syncthreads();
    }
    if (t < 128) {
        exs[t] = sc[t] - hist[t];
        cur[t] = 0;
    }
    __syncthreads();
    if (t < nloc) {
        row_ptr[b * 128 + t] = start + exs[t];
        dis[b * 128 + t] = rsqrtf((float)hist[t]);
    }
    for (int i = t; i < cnt; i += 256) {
        uint e = binned[start + i];
        int dl = (e >> 16) & 127;
        int pos = start + exs[dl] + atomicAdd(&cur[dl], 1);
        csr_src[pos] = (ushort)(e & 0xFFFFu);
    }
}

// ---------------------------------------------------------------------------
// Weight packing: W[K][N] fp32 -> fragment-ordered bf16 hi/lo
// ---------------------------------------------------------------------------

__device__ __forceinline__ void pack_w_body(const float* W, ushort* Ph, ushort* Pl,
                                            int K, int N, int bb, int lane) {
    int CT = N / 16;
    int ct = bb % CT;
    int kt = bb / CT;
    int lr = lane & 15, lg = lane >> 4;
    size_t base = ((size_t)bb * 64 + lane) * 8;
#pragma unroll
    for (int j = 0; j < 8; j++) {
        float w = W[(size_t)(kt * 32 + lg * 8 + j) * N + ct * 16 + lr];
        ushort h = f2bf(w);
        ushort lo = f2bf(w - bf2f(h));
        Ph[base + j] = h;
        Pl[base + j] = lo;
    }
}

__global__ __launch_bounds__(64) void pack_w_kernel(const float* __restrict__ W,
                                                    ushort* __restrict__ Ph,
                                                    ushort* __restrict__ Pl,
                                                    int K, int N) {
    pack_w_body(W, Ph, Pl, K, N, blockIdx.x, threadIdx.x);
}

// The three conv weights (identical shape) in one launch: 32 blocks each.
__global__ __launch_bounds__(64) void pack_w3_kernel(const float* __restrict__ W0,
                                                     const float* __restrict__ W1,
                                                     const float* __restrict__ W2,
                                                     ushort* __restrict__ P0h, ushort* __restrict__ P0l,
                                                     ushort* __restrict__ P1h, ushort* __restrict__ P1l,
                                                     ushort* __restrict__ P2h, ushort* __restrict__ P2l) {
    int l = blockIdx.x >> 5;
    int bb = blockIdx.x & 31;
    const float* W = (l == 0) ? W0 : (l == 1) ? W1 : W2;
    ushort* Ph = (l == 0) ? P0h : (l == 1) ? P1h : P2h;
    ushort* Pl = (l == 0) ? P0l : (l == 1) ? P1l : P2l;
    pack_w_body(W, Ph, Pl, HID_C, HID_C, bb, threadIdx.x);
}

// ---------------------------------------------------------------------------
// LDS-free MFMA GEMM, 3-term bf16 split, packed activations, MT=2 m-tiles
// per wave. N=128: block = 64 rows, grid 782. N=64: block = 128 rows, grid 391.
// OUT_MODE: 0 = fp32 + bias, 1 = packed uint + bias, 2 = fp16 * dis[row]
// ---------------------------------------------------------------------------

template <int K, int N, int OUT_MODE, bool AF32>
__global__ __launch_bounds__(256) void gemm_mfma_kernel(
    const float* __restrict__ Af, const uint* __restrict__ Ax,
    const ushort* __restrict__ Wph, const ushort* __restrict__ Wpl,
    const float* __restrict__ bias, const float* __restrict__ disp,
    float* __restrict__ Cf, uint* __restrict__ Cx, _Float16* __restrict__ Ch,
    int M) {
    constexpr int CT_TOT = N / 16;
    constexpr int NWC = CT_TOT / 4;
    constexpr int NWR = 4 / NWC;
    constexpr int KT = K / 32;
    constexpr int MT = 2;
    constexpr int RPB = NWR * MT * 16;

    const int wid = threadIdx.x >> 6;
    const int lane = threadIdx.x & 63;
    const int lr = lane & 15;
    const int lg = lane >> 4;
    const int wr = (NWC == 1) ? wid : (wid >> 1);
    const int wc = (NWC == 1) ? 0 : (wid & 1);
    const int row_base = blockIdx.x * RPB + wr * (MT * 16);
    const int ct0 = wc * 4;

    f32x4 acc[MT][4];
#pragma unroll
    for (int mt = 0; mt < MT; mt++)
#pragma unroll
        for (int ct = 0; ct < 4; ct++) acc[mt][ct] = (f32x4){0.f, 0.f, 0.f, 0.f};

    int rr_[MT];
#pragma unroll
    for (int mt = 0; mt < MT; mt++) {
        int r = row_base + mt * 16 + lr;
        rr_[mt] = (r >= M) ? (M - 1) : r;
    }

    uint4 apk[AF32 ? 1 : KT][MT][2];
    float4 v0a[MT], v1a[MT];
    if (AF32) {
#pragma unroll
        for (int mt = 0; mt < MT; mt++) {
            const float* ap = &Af[(size_t)rr_[mt] * K + lg * 8];
            v0a[mt] = *(const float4*)ap;
            v1a[mt] = *(const float4*)(ap + 4);
        }
    } else {
#pragma unroll
        for (int kt = 0; kt < KT; kt++)
#pragma unroll
            for (int mt = 0; mt < MT; mt++) {
                const uint* ab = &Ax[(size_t)rr_[mt] * K + lg * 8];
                apk[kt][mt][0] = *(const uint4*)(ab + kt * 32);
                apk[kt][mt][1] = *(const uint4*)(ab + kt * 32 + 4);
            }
    }

#pragma unroll
    for (int kt = 0; kt < KT; kt++) {
        const ushort* bh = &Wph[((size_t)kt * CT_TOT + ct0) * 512 + (size_t)lane * 8];
        const ushort* bl = &Wpl[((size_t)kt * CT_TOT + ct0) * 512 + (size_t)lane * 8];
        bf16x8 bhv[4], blv[4];
#pragma unroll
        for (int ct = 0; ct < 4; ct++) {
            bhv[ct] = *(const bf16x8*)(bh + ct * 512);
            blv[ct] = *(const bf16x8*)(bl + ct * 512);
        }

        bf16x8 ah[MT], al[MT];
#pragma unroll
        for (int mt = 0; mt < MT; mt++) {
            if (AF32) {
                float4 v0c = v0a[mt], v1c = v1a[mt];
                if (kt + 1 < KT) {
                    const float* ap = &Af[(size_t)rr_[mt] * K + (kt + 1) * 32 + lg * 8];
                    v0a[mt] = *(const float4*)ap;
                    v1a[mt] = *(const float4*)(ap + 4);
                }
                float av[8] = {v0c.x, v0c.y, v0c.z, v0c.w, v1c.x, v1c.y, v1c.z, v1c.w};
#pragma unroll
                for (int j = 0; j < 8; j++) {
                    ushort h = f2bf(av[j]);
                    ushort lo = f2bf(av[j] - bf2f(h));
                    ah[mt][j] = (short)h;
                    al[mt][j] = (short)lo;
                }
            } else {
                union { uint u[4]; bf16x8 v; } ch_, cl_;
#pragma unroll
                for (int j = 0; j < 4; j++) {
                    uint u0 = (j < 2) ? ((const uint*)&apk[kt][mt][0])[j * 2]
                                      : ((const uint*)&apk[kt][mt][1])[(j - 2) * 2];
                    uint u1 = (j < 2) ? ((const uint*)&apk[kt][mt][0])[j * 2 + 1]
                                      : ((const uint*)&apk[kt][mt][1])[(j - 2) * 2 + 1];
                    ch_.u[j] = (u0 >> 16) | (u1 & 0xFFFF0000u);
                    cl_.u[j] = (u0 & 0xFFFFu) | (u1 << 16);
                }
                ah[mt] = ch_.v;
                al[mt] = cl_.v;
            }
        }

#pragma unroll
        for (int mt = 0; mt < MT; mt++)
#pragma unroll
            for (int ct = 0; ct < 4; ct++) {
                acc[mt][ct] = __builtin_amdgcn_mfma_f32_16x16x32_bf16(ah[mt], bhv[ct], acc[mt][ct], 0, 0, 0);
                acc[mt][ct] = __builtin_amdgcn_mfma_f32_16x16x32_bf16(al[mt], bhv[ct], acc[mt][ct], 0, 0, 0);
                acc[mt][ct] = __builtin_amdgcn_mfma_f32_16x16x32_bf16(ah[mt], blv[ct], acc[mt][ct], 0, 0, 0);
            }
    }

#pragma unroll
    for (int mt = 0; mt < MT; mt++)
#pragma unroll
        for (int ct = 0; ct < 4; ct++)
#pragma unroll
            for (int j = 0; j < 4; j++) {
                int rr = row_base + mt * 16 + lg * 4 + j;
                if (rr >= M) continue;
                int c = (ct0 + ct) * 16 + lr;
                float v = acc[mt][ct][j];
                if (OUT_MODE == 2) {
                    Ch[(size_t)rr * N + c] = (_Float16)(v * disp[rr]);
                } else if (OUT_MODE == 1) {
                    Cx[(size_t)rr * N + c] = packhl(v + bias[c]);
                } else {
                    Cf[(size_t)rr * N + c] = v + bias[c];
                }
            }
}

// ---------------------------------------------------------------------------
// CSR aggregation: wave = node, 64 lanes x f16x2 = full 128-ch fp16 row
// (256 B) per instruction. Unroll-16 main loop = 64 cache lines in flight
// per wave (restores the line-level MLP the fp32 version had).
// g pre-scaled by dis[src] in GEMM epilogue.
// out = relu(dis[node]*sum + bias) -> packed uint (uint2/lane, 512 B/wave).
// ---------------------------------------------------------------------------

__global__ __launch_bounds__(256) void aggregate_kernel(const _Float16* __restrict__ g,
                                                        const int* __restrict__ row_ptr,
                                                        const ushort* __restrict__ csr_src,
                                                        const float* __restrict__ dis,
                                                        const float* __restrict__ bias,
                                                        uint* __restrict__ hx) {
    const int wid = threadIdx.x >> 6;
    const int lane = threadIdx.x & 63;
    const int node = blockIdx.x * 4 + wid;
    if (node >= N_NODES) return;
    const int c2 = lane * 2;

    const int s0 = row_ptr[node];
    const int s1 = row_ptr[node + 1];

    float ax = 0.f, ay = 0.f;
    int e = s0;
    for (; e + 16 <= s1; e += 16) {
        int idx[16];
#pragma unroll
        for (int j = 0; j < 16; j++) idx[j] = csr_src[e + j];
        f16x2 v[16];
#pragma unroll
        for (int j = 0; j < 16; j++)
            v[j] = *(const f16x2*)&g[(size_t)idx[j] * HID_C + c2];
        float sx = 0.f, sy = 0.f;
#pragma unroll
        for (int j = 0; j < 16; j++) {
            sx += (float)v[j].x;
            sy += (float)v[j].y;
        }
        ax += sx;
        ay += sy;
    }
    for (; e + 4 <= s1; e += 4) {
        int idx[4];
#pragma unroll
        for (int j = 0; j < 4; j++) idx[j] = csr_src[e + j];
        f16x2 v[4];
#pragma unroll
        for (int j = 0; j < 4; j++)
            v[j] = *(const f16x2*)&g[(size_t)idx[j] * HID_C + c2];
        ax += ((float)v[0].x + (float)v[1].x) + ((float)v[2].x + (float)v[3].x);
        ay += ((float)v[0].y + (float)v[1].y) + ((float)v[2].y + (float)v[3].y);
    }
    for (; e < s1; e++) {
        int i0 = csr_src[e];
        f16x2 v0 = *(const f16x2*)&g[(size_t)i0 * HID_C + c2];
        ax += (float)v0.x;
        ay += (float)v0.y;
    }

    const float dn = dis[node];
    float2 bb = *(const float2*)&bias[c2];
    float vx = fmaxf(dn * ax + bb.x, 0.f);
    float vy = fmaxf(dn * ay + bb.y, 0.f);
    uint2 w;
    w.x = packhl(vx);
    w.y = packhl(vy);
    *(uint2*)&hx[(size_t)node * HID_C + c2] = w;
}

// ---------------------------------------------------------------------------
// Launch
// ---------------------------------------------------------------------------

extern "C" void kernel_launch(void* const* d_in, const int* in_sizes, int n_in,
                              void* d_out, int out_size, void* d_ws, size_t ws_size,
                              hipStream_t stream) {
    const float* x       = (const float*)d_in[0];
    const int*   eidx    = (const int*)d_in[1];
    const float* proj_W  = (const float*)d_in[2];
    const float* proj_b  = (const float*)d_in[3];
    const float* conv_W0 = (const float*)d_in[4];
    const float* conv_b0 = (const float*)d_in[5];
    const float* conv_W1 = (const float*)d_in[6];
    const float* conv_b1 = (const float*)d_in[7];
    const float* conv_W2 = (const float*)d_in[8];
    const float* conv_b2 = (const float*)d_in[9];
    const float* out_W   = (const float*)d_in[10];
    const float* out_b   = (const float*)d_in[11];
    float* out = (float*)d_out;

    const int* src = eidx;
    const int* dst = eidx + N_EDGES;

    char* ws = (char*)d_ws;
    size_t off = 0;
    auto carve = [&](size_t bytes) {
        void* p = ws + off;
        off += (bytes + 255) & ~(size_t)255;
        return p;
    };
    int*    row_ptr  = (int*)carve((N_NODES + 1) * sizeof(int));
    ushort* csr_src  = (ushort*)carve((size_t)N_TOT * sizeof(ushort));
    uint*   binned   = (uint*)carve((size_t)N_TOT * sizeof(uint));
    int*    binhist  = (int*)carve(N_BINS * sizeof(int));
    int*    bin_base = (int*)carve((N_BINS + 1) * sizeof(int));
    int*    bincur   = (int*)carve(N_BINS * sizeof(int));
    float*  dis      = (float*)carve(N_NODES * sizeof(float));
    ushort* projPh = (ushort*)carve((size_t)IN_C * HID_C * sizeof(ushort));
    ushort* projPl = (ushort*)carve((size_t)IN_C * HID_C * sizeof(ushort));
    ushort* convPh[3], *convPl[3];
    for (int l = 0; l < 3; l++) {
        convPh[l] = (ushort*)carve((size_t)HID_C * HID_C * sizeof(ushort));
        convPl[l] = (ushort*)carve((size_t)HID_C * HID_C * sizeof(ushort));
    }
    ushort* outPh = (ushort*)carve((size_t)HID_C * OUT_C * sizeof(ushort));
    ushort* outPl = (ushort*)carve((size_t)HID_C * OUT_C * sizeof(ushort));
    uint*   hx = (uint*)carve((size_t)N_NODES * HID_C * sizeof(uint));
    _Float16* g = (_Float16*)carve((size_t)N_NODES * HID_C * sizeof(_Float16));

    // Graph preprocessing (bin-centric)
    zero_binhist_kernel<<<(N_BINS + 255) / 256, 256, 0, stream>>>(binhist);
    bin_hist_kernel<<<196, 256, 0, stream>>>(dst, binhist);
    bin_scan_kernel<<<1, 512, 0, stream>>>(binhist, bin_base, bincur, row_ptr);
    bin_scatter_kernel<<<RB_GRID, RB_BLOCK, 0, stream>>>(
        src, dst, bin_base, bincur, binned);
    csr_build_kernel<<<N_BINS, 256, 0, stream>>>(
        binned, bin_base, row_ptr, dis, csr_src);

    // Weight packing
    pack_w_kernel<<<(IN_C / 32) * (HID_C / 16), 64, 0, stream>>>(proj_W, projPh, projPl, IN_C, HID_C);
    pack_w3_kernel<<<3 * 32, 64, 0, stream>>>(conv_W0, conv_W1, conv_W2,
                                              convPh[0], convPl[0],
                                              convPh[1], convPl[1],
                                              convPh[2], convPl[2]);
    pack_w_kernel<<<(HID_C / 32) * (OUT_C / 16), 64, 0, stream>>>(out_W, outPh, outPl, HID_C, OUT_C);

    const int grid_n128 = (N_NODES + 63) / 64;    // 782
    const int grid_n64  = (N_NODES + 127) / 128;  // 391
    const int agg_grid  = (N_NODES + 3) / 4;      // 12500

    // Projection: hx = pack(x @ proj_W + proj_b)
    gemm_mfma_kernel<IN_C, HID_C, 1, true><<<grid_n128, 256, 0, stream>>>(
        x, nullptr, projPh, projPl, proj_b, nullptr, nullptr, hx, nullptr, N_NODES);

    // 3 GCN layers
    ushort* Wh_[3] = {convPh[0], convPh[1], convPh[2]};
    ushort* Wl_[3] = {convPl[0], convPl[1], convPl[2]};
    const float* bs_[3] = {conv_b0, conv_b1, conv_b2};
    for (int l = 0; l < 3; l++) {
        // g[node][128] = fp16(dis[node] * (h @ W)[node])
        gemm_mfma_kernel<HID_C, HID_C, 2, false><<<grid_n128, 256, 0, stream>>>(
            nullptr, hx, Wh_[l], Wl_[l], nullptr, dis, nullptr, nullptr, g, N_NODES);
        aggregate_kernel<<<agg_grid, 256, 0, stream>>>(
            g, row_ptr, csr_src, dis, bs_[l], hx);
    }

    // Output: out = h @ out_W + out_b (fp32)
    gemm_mfma_kernel<HID_C, OUT_C, 0, false><<<grid_n64, 256, 0, stream>>>(
        nullptr, hx, outPh, outPl, out_b, nullptr, out, nullptr, nullptr, N_NODES);
}